// Round 1
// baseline (3324.071 us; speedup 1.0000x reference)
//
#include <hip/hip_runtime.h>

#define EPS 1e-7f

static __host__ __device__ inline int cdiv_i(int a, int b) { return (a + b - 1) / b; }

// Soft-splat accumulate: one thread per source pixel, loops channels.
// feat [N,C,H,W], flow [N,2,H,W], metric [N,1,H,W]
// num [N,C,H,W] accumulators, denom [N,H,W], hole [N,H,W] (weight-only sums)
template <int C, bool HOLE>
__global__ void splat_kernel(const float* __restrict__ feat, float feat_scale,
                             const float* __restrict__ flow, float flow_scale,
                             const float* __restrict__ metric,
                             float* __restrict__ num,
                             float* __restrict__ denom,
                             float* __restrict__ hole,
                             int N, int H, int W) {
    const int HW = H * W;
    int idx = blockIdx.x * blockDim.x + threadIdx.x;
    if (idx >= N * HW) return;
    int n = idx / HW;
    int p = idx - n * HW;
    int y = p / W;
    int x = p - y * W;

    float dx = flow[(size_t)(n * 2 + 0) * HW + p] * flow_scale;
    float dy = flow[(size_t)(n * 2 + 1) * HW + p] * flow_scale;
    float m  = metric[(size_t)n * HW + p];
    float e  = expf(fminf(fmaxf(-m, -20.0f), 20.0f));

    float gx = (float)x + dx;
    float gy = (float)y + dy;
    float x0f = floorf(gx), y0f = floorf(gy);
    float fx = gx - x0f, fy = gy - y0f;
    int x0 = (int)x0f, y0 = (int)y0f;

    float wgt[4] = { (1.0f - fx) * (1.0f - fy), fx * (1.0f - fy),
                     (1.0f - fx) * fy,          fx * fy };
    int cx[4] = { x0, x0 + 1, x0,     x0 + 1 };
    int cy[4] = { y0, y0,     y0 + 1, y0 + 1 };
    int  tgt[4];
    bool val[4];

    float* denom_n = denom + (size_t)n * HW;
#pragma unroll
    for (int k = 0; k < 4; ++k) {
        val[k] = (cx[k] >= 0) && (cx[k] < W) && (cy[k] >= 0) && (cy[k] < H);
        tgt[k] = cy[k] * W + cx[k];
        if (val[k]) {
            atomicAdd(&denom_n[tgt[k]], wgt[k] * e);
            if (HOLE) atomicAdd(&hole[(size_t)n * HW + tgt[k]], wgt[k]);
        }
    }

    for (int c = 0; c < C; ++c) {
        float v = feat[((size_t)n * C + c) * HW + p] * feat_scale * e;
        float* num_c = num + ((size_t)n * C + c) * HW;
#pragma unroll
        for (int k = 0; k < 4; ++k) {
            if (val[k]) atomicAdd(&num_c[tgt[k]], wgt[k] * v);
        }
    }
}

// out = sign * num / (denom + EPS), in place on num. Layout [N,C,HW].
__global__ void normalize_kernel(float* __restrict__ num, const float* __restrict__ denom,
                                 int C, int HW, int total, float sign) {
    int idx = blockIdx.x * blockDim.x + threadIdx.x;
    if (idx >= total) return;
    int n = idx / (C * HW);
    int p = idx % HW;
    num[idx] = sign * (num[idx] / (denom[(size_t)n * HW + p] + EPS));
}

// binary hole: s -> (s/(s+EPS) <= 0.5) ? 1 : 0, in place
__global__ void hole_kernel(float* __restrict__ buf, int total) {
    int idx = blockIdx.x * blockDim.x + threadIdx.x;
    if (idx >= total) return;
    float s = buf[idx];
    float mask = s / (s + EPS);
    buf[idx] = (mask <= 0.5f) ? 1.0f : 0.0f;
}

// Exact factor-2 bilinear+antialias downsample (jax.image.resize semantics):
// separable 4-tap kernel values {0.25,0.75,0.75,0.25} at taps 2i-1..2i+2,
// per-axis renormalized over in-bounds taps. Output scaled by `scale`.
__global__ void downsample2_kernel(const float* __restrict__ in, float* __restrict__ out,
                                   int NC, int Hin, int Win, float scale) {
    const int Hout = Hin >> 1, Wout = Win >> 1;
    const int HWo = Hout * Wout;
    int idx = blockIdx.x * blockDim.x + threadIdx.x;
    if (idx >= NC * HWo) return;
    int nc = idx / HWo;
    int p = idx - nc * HWo;
    int i = p / Wout;
    int j = p - i * Wout;

    const float kk[4] = { 0.25f, 0.75f, 0.75f, 0.25f };
    float wy[4], wx[4], sy = 0.0f, sx = 0.0f;
    int r0 = 2 * i - 1, c0 = 2 * j - 1;
#pragma unroll
    for (int a = 0; a < 4; ++a) {
        int ra = r0 + a;
        wy[a] = (ra >= 0 && ra < Hin) ? kk[a] : 0.0f;
        sy += wy[a];
        int cb = c0 + a;
        wx[a] = (cb >= 0 && cb < Win) ? kk[a] : 0.0f;
        sx += wx[a];
    }
#pragma unroll
    for (int a = 0; a < 4; ++a) { wy[a] /= sy; wx[a] /= sx; }

    const float* base = in + (size_t)nc * Hin * Win;
    float acc = 0.0f;
#pragma unroll
    for (int a = 0; a < 4; ++a) {
        int ra = r0 + a;
        if (ra < 0 || ra >= Hin) continue;
        const float* row = base + (size_t)ra * Win;
        float racc = 0.0f;
#pragma unroll
        for (int b = 0; b < 4; ++b) {
            int cb = c0 + b;
            if (cb < 0 || cb >= Win) continue;
            racc += wx[b] * row[cb];
        }
        acc += wy[a] * racc;
    }
    out[(size_t)nc * HWo + p] = acc * scale;
}

extern "C" void kernel_launch(void* const* d_in, const int* in_sizes, int n_in,
                              void* d_out, int out_size, void* d_ws, size_t ws_size,
                              hipStream_t stream) {
    // dict order: x1_0, x2_0, x1_1, x2_1, x1_2, x2_2, m1t, m2t, F12, F21
    const float* x1_0 = (const float*)d_in[0];
    const float* x1_1 = (const float*)d_in[2];
    const float* x1_2 = (const float*)d_in[4];
    const float* m1t  = (const float*)d_in[6];
    const float* m2t  = (const float*)d_in[7];
    const float* F12  = (const float*)d_in[8];
    const float* F21  = (const float*)d_in[9];

    const int N = 4;
    const int H0 = 256, W0 = 448;
    const int H1 = 128, W1 = 224;
    const int H2 = 64,  W2 = 112;
    const int HW0 = H0 * W0, HW1 = H1 * W1, HW2 = H2 * W2;
    const int NHW0 = N * HW0, NHW1 = N * HW1, NHW2 = N * HW2;

    // d_out layout (floats), in reference return order
    const size_t o0 = 0;                                  // warped0 [4,32,256,448]
    const size_t o1 = o0 + (size_t)N * 32 * HW0;          // warped1 [4,64,128,224]
    const size_t o2 = o1 + (size_t)N * 64 * HW1;          // warped2 [4,96,64,112]
    const size_t o3 = o2 + (size_t)N * 96 * HW2;          // bmask0  [4,1,256,448]
    const size_t o4 = o3 + (size_t)NHW0;                  // bmask1  [4,1,128,224]
    const size_t o5 = o4 + (size_t)NHW1;                  // bmask2  [4,1,64,112]
    const size_t o6 = o5 + (size_t)NHW2;                  // Ft2     [4,2,256,448]
    float* out = (float*)d_out;

    // ws layout (floats)
    float* ws_f     = (float*)d_ws;
    float* denom0   = ws_f;                 // NHW0
    float* denom1   = denom0 + NHW0;        // NHW1
    float* denom2   = denom1 + NHW1;        // NHW2
    float* denomF   = denom2 + NHW2;        // NHW0
    float* metric1  = denomF + NHW0;        // NHW1
    float* metric2  = metric1 + NHW1;       // NHW2
    float* flow1    = metric2 + NHW2;       // 2*NHW1
    float* flow2    = flow1 + 2 * NHW1;     // 2*NHW2
    const size_t zeroN = (size_t)NHW0 + NHW1 + NHW2 + NHW0;

    // zero accumulators (numerators live in d_out, hole sums in bmask slots)
    hipMemsetAsync(d_out, 0, (size_t)out_size * sizeof(float), stream);
    hipMemsetAsync(ws_f, 0, zeroN * sizeof(float), stream);

    const int B = 256;

    // pyramid resizes: metric (no scale), flow (scale=0.5 per level).
    // F1t = 0.5*F12 folded into scales: flow1 = down(F12)*0.25; flow2 = down(flow1)*0.5
    downsample2_kernel<<<cdiv_i(N * 1 * HW1, B), B, 0, stream>>>(m1t, metric1, N, H0, W0, 1.0f);
    downsample2_kernel<<<cdiv_i(N * 2 * HW1, B), B, 0, stream>>>(F12, flow1, N * 2, H0, W0, 0.25f);
    downsample2_kernel<<<cdiv_i(N * 1 * HW2, B), B, 0, stream>>>(metric1, metric2, N, H1, W1, 1.0f);
    downsample2_kernel<<<cdiv_i(N * 2 * HW2, B), B, 0, stream>>>(flow1, flow2, N * 2, H1, W1, 0.5f);

    // splats (metric scale 2t = 2(1-t) = 1.0 at t=0.5)
    splat_kernel<32, true><<<cdiv_i(NHW0, B), B, 0, stream>>>(
        x1_0, 1.0f, F12, 0.5f, m1t, out + o0, denom0, out + o3, N, H0, W0);
    splat_kernel<64, true><<<cdiv_i(NHW1, B), B, 0, stream>>>(
        x1_1, 1.0f, flow1, 1.0f, metric1, out + o1, denom1, out + o4, N, H1, W1);
    splat_kernel<96, true><<<cdiv_i(NHW2, B), B, 0, stream>>>(
        x1_2, 1.0f, flow2, 1.0f, metric2, out + o2, denom2, out + o5, N, H2, W2);
    // Ft2 = -softsplat(F2t, F2t, clip(-m2t,-20,20), soft), F2t = 0.5*F21
    splat_kernel<2, false><<<cdiv_i(NHW0, B), B, 0, stream>>>(
        F21, 0.5f, F21, 0.5f, m2t, out + o6, denomF, nullptr, N, H0, W0);

    // normalize
    normalize_kernel<<<cdiv_i(N * 32 * HW0, B), B, 0, stream>>>(out + o0, denom0, 32, HW0, N * 32 * HW0, 1.0f);
    normalize_kernel<<<cdiv_i(N * 64 * HW1, B), B, 0, stream>>>(out + o1, denom1, 64, HW1, N * 64 * HW1, 1.0f);
    normalize_kernel<<<cdiv_i(N * 96 * HW2, B), B, 0, stream>>>(out + o2, denom2, 96, HW2, N * 96 * HW2, 1.0f);
    normalize_kernel<<<cdiv_i(N * 2 * HW0, B), B, 0, stream>>>(out + o6, denomF, 2, HW0, N * 2 * HW0, -1.0f);

    // hole masks
    hole_kernel<<<cdiv_i(NHW0, B), B, 0, stream>>>(out + o3, NHW0);
    hole_kernel<<<cdiv_i(NHW1, B), B, 0, stream>>>(out + o4, NHW1);
    hole_kernel<<<cdiv_i(NHW2, B), B, 0, stream>>>(out + o5, NHW2);
}

// Round 2
// 948.086 us; speedup vs baseline: 3.5061x; 3.5061x over previous
//
#include <hip/hip_runtime.h>

#define EPS 1e-7f

static inline int cdiv_i(int a, int b) { return (a + b - 1) / b; }

// ---------------------------------------------------------------------------
// Exact factor-2 bilinear+antialias downsample (jax.image.resize semantics)
// ---------------------------------------------------------------------------
__global__ void downsample2_kernel(const float* __restrict__ in, float* __restrict__ out,
                                   int NC, int Hin, int Win, float scale) {
    const int Hout = Hin >> 1, Wout = Win >> 1;
    const int HWo = Hout * Wout;
    int idx = blockIdx.x * blockDim.x + threadIdx.x;
    if (idx >= NC * HWo) return;
    int nc = idx / HWo;
    int p = idx - nc * HWo;
    int i = p / Wout;
    int j = p - i * Wout;

    const float kk[4] = { 0.25f, 0.75f, 0.75f, 0.25f };
    float wy[4], wx[4], sy = 0.0f, sx = 0.0f;
    int r0 = 2 * i - 1, c0 = 2 * j - 1;
#pragma unroll
    for (int a = 0; a < 4; ++a) {
        int ra = r0 + a;
        wy[a] = (ra >= 0 && ra < Hin) ? kk[a] : 0.0f;
        sy += wy[a];
        int cb = c0 + a;
        wx[a] = (cb >= 0 && cb < Win) ? kk[a] : 0.0f;
        sx += wx[a];
    }
#pragma unroll
    for (int a = 0; a < 4; ++a) { wy[a] /= sy; wx[a] /= sx; }

    const float* base = in + (size_t)nc * Hin * Win;
    float acc = 0.0f;
#pragma unroll
    for (int a = 0; a < 4; ++a) {
        int ra = r0 + a;
        if (ra < 0 || ra >= Hin) continue;
        const float* row = base + (size_t)ra * Win;
        float racc = 0.0f;
#pragma unroll
        for (int b = 0; b < 4; ++b) {
            int cb = c0 + b;
            if (cb < 0 || cb >= Win) continue;
            racc += wx[b] * row[cb];
        }
        acc += wy[a] * racc;
    }
    out[(size_t)nc * HWo + p] = acc * scale;
}

// ---------------------------------------------------------------------------
// NCHW -> NHWC(stride CS) feature transpose. 64 px tile per block, 256 thr.
// ---------------------------------------------------------------------------
template <int C, int CS, int CSP>
__global__ void t_nchw2nhwc(const float* __restrict__ in, float* __restrict__ out, int HW) {
    __shared__ float lds[64 * CSP];
    int q0 = blockIdx.x * 64;              // global pixel (n*HW + p)
    int n = q0 / HW;
    int p0 = q0 - n * HW;
    int l = threadIdx.x & 63;
    int cg = threadIdx.x >> 6;
    for (int c = cg; c < C; c += 4) {
        lds[l * CSP + c] = in[((size_t)n * C + c) * HW + p0 + l];
    }
    __syncthreads();
    const int TOT = 64 * CS;
    for (int idx = threadIdx.x; idx < TOT; idx += 256) {
        int px = idx / CS;
        int c = idx - px * CS;
        out[(size_t)q0 * CS + idx] = (c < C) ? lds[px * CSP + c] : 0.0f;
    }
}

// ---------------------------------------------------------------------------
// Coalesced NHWC soft-splat. Channels innermost; c==C carries denom (e),
// c==C+1 carries hole weight (1). LPP lanes per pixel (power of 2).
// ---------------------------------------------------------------------------
template <int C, int CS, int LPP, bool HOLE, bool FLOWFEAT>
__global__ void splat_nhwc(const float* __restrict__ featT, float feat_scale,
                           const float* __restrict__ flow, float flow_scale,
                           const float* __restrict__ metric,
                           float* __restrict__ num,
                           int N, int H, int W) {
    const int HW = H * W;
    const int CA = C + 1 + (HOLE ? 1 : 0);
    const int PPW = 64 / LPP;
    int lane = threadIdx.x & 63;
    int wave = threadIdx.x >> 6;
    int lane_c = lane & (LPP - 1);
    int px_in_wave = lane / LPP;
    int q = blockIdx.x * (4 * PPW) + wave * PPW + px_in_wave;
    if (q >= N * HW) return;
    int n = q / HW;
    int p = q - n * HW;
    int y = p / W;
    int x = p - y * W;

    float dx = flow[((size_t)n * 2 + 0) * HW + p] * flow_scale;
    float dy = flow[((size_t)n * 2 + 1) * HW + p] * flow_scale;
    float m  = metric[(size_t)n * HW + p];
    float e  = expf(fminf(fmaxf(-m, -20.0f), 20.0f));

    float gx = (float)x + dx;
    float gy = (float)y + dy;
    float x0f = floorf(gx), y0f = floorf(gy);
    float fx = gx - x0f, fy = gy - y0f;
    int x0 = (int)x0f, y0 = (int)y0f;

    float wgt[4] = { (1.0f - fx) * (1.0f - fy), fx * (1.0f - fy),
                     (1.0f - fx) * fy,          fx * fy };
    int cx[4] = { x0, x0 + 1, x0,     x0 + 1 };
    int cy[4] = { y0, y0,     y0 + 1, y0 + 1 };
    size_t tgt[4];
    bool val[4];
#pragma unroll
    for (int k = 0; k < 4; ++k) {
        val[k] = (cx[k] >= 0) && (cx[k] < W) && (cy[k] >= 0) && (cy[k] < H);
        tgt[k] = ((size_t)((n * H + cy[k]) * W + cx[k])) * CS;
    }

    for (int c = lane_c; c < CA; c += LPP) {
        float v;
        if (c < C) {
            float f = FLOWFEAT ? (c == 0 ? dx : dy)
                               : featT[(size_t)q * CS + c] * feat_scale;
            v = f * e;
        } else if (c == C) {
            v = e;            // denominator channel
        } else {
            v = 1.0f;         // hole-weight channel (times wgt below)
        }
#pragma unroll
        for (int k = 0; k < 4; ++k) {
            if (val[k]) atomicAdd(&num[tgt[k] + c], wgt[k] * v);
        }
    }
}

// ---------------------------------------------------------------------------
// NHWC accum -> NCHW normalized output (+ optional hole mask). 64 px / block.
// ---------------------------------------------------------------------------
template <int C, int CS, int CSP, bool HOLE>
__global__ void norm_nhwc2nchw(const float* __restrict__ num, float* __restrict__ out,
                               float* __restrict__ hole_out, int HW, float sign) {
    __shared__ float lds[64 * CSP];
    int q0 = blockIdx.x * 64;
    int n = q0 / HW;
    int p0 = q0 - n * HW;
    const int TOT = 64 * CS;
    for (int idx = threadIdx.x; idx < TOT; idx += 256) {
        int px = idx / CS;
        int c = idx - px * CS;
        lds[px * CSP + c] = num[(size_t)q0 * CS + idx];
    }
    __syncthreads();
    int l = threadIdx.x & 63;
    int cg = threadIdx.x >> 6;
    float inv = sign / (lds[l * CSP + C] + EPS);
    for (int c = cg; c < C; c += 4) {
        out[((size_t)n * C + c) * HW + p0 + l] = lds[l * CSP + c] * inv;
    }
    if (HOLE && threadIdx.x < 64) {
        float s = lds[threadIdx.x * CSP + C + 1];
        float mask = s / (s + EPS);
        hole_out[q0 + threadIdx.x] = (mask <= 0.5f) ? 1.0f : 0.0f;
    }
}

// ---------------------------------------------------------------------------
// Fallback path (round-1 kernels) if ws is too small
// ---------------------------------------------------------------------------
template <int C, bool HOLE>
__global__ void splat_kernel(const float* __restrict__ feat, float feat_scale,
                             const float* __restrict__ flow, float flow_scale,
                             const float* __restrict__ metric,
                             float* __restrict__ num,
                             float* __restrict__ denom,
                             float* __restrict__ hole,
                             int N, int H, int W) {
    const int HW = H * W;
    int idx = blockIdx.x * blockDim.x + threadIdx.x;
    if (idx >= N * HW) return;
    int n = idx / HW;
    int p = idx - n * HW;
    int y = p / W;
    int x = p - y * W;

    float dx = flow[(size_t)(n * 2 + 0) * HW + p] * flow_scale;
    float dy = flow[(size_t)(n * 2 + 1) * HW + p] * flow_scale;
    float m  = metric[(size_t)n * HW + p];
    float e  = expf(fminf(fmaxf(-m, -20.0f), 20.0f));

    float gx = (float)x + dx;
    float gy = (float)y + dy;
    float x0f = floorf(gx), y0f = floorf(gy);
    float fx = gx - x0f, fy = gy - y0f;
    int x0 = (int)x0f, y0 = (int)y0f;

    float wgt[4] = { (1.0f - fx) * (1.0f - fy), fx * (1.0f - fy),
                     (1.0f - fx) * fy,          fx * fy };
    int cx[4] = { x0, x0 + 1, x0,     x0 + 1 };
    int cy[4] = { y0, y0,     y0 + 1, y0 + 1 };
    int  tgt[4];
    bool val[4];

    float* denom_n = denom + (size_t)n * HW;
#pragma unroll
    for (int k = 0; k < 4; ++k) {
        val[k] = (cx[k] >= 0) && (cx[k] < W) && (cy[k] >= 0) && (cy[k] < H);
        tgt[k] = cy[k] * W + cx[k];
        if (val[k]) {
            atomicAdd(&denom_n[tgt[k]], wgt[k] * e);
            if (HOLE) atomicAdd(&hole[(size_t)n * HW + tgt[k]], wgt[k]);
        }
    }
    for (int c = 0; c < C; ++c) {
        float v = feat[((size_t)n * C + c) * HW + p] * feat_scale * e;
        float* num_c = num + ((size_t)n * C + c) * HW;
#pragma unroll
        for (int k = 0; k < 4; ++k) {
            if (val[k]) atomicAdd(&num_c[tgt[k]], wgt[k] * v);
        }
    }
}

__global__ void normalize_kernel(float* __restrict__ num, const float* __restrict__ denom,
                                 int C, int HW, int total, float sign) {
    int idx = blockIdx.x * blockDim.x + threadIdx.x;
    if (idx >= total) return;
    int n = idx / (C * HW);
    int p = idx % HW;
    num[idx] = sign * (num[idx] / (denom[(size_t)n * HW + p] + EPS));
}

__global__ void hole_kernel(float* __restrict__ buf, int total) {
    int idx = blockIdx.x * blockDim.x + threadIdx.x;
    if (idx >= total) return;
    float s = buf[idx];
    float mask = s / (s + EPS);
    buf[idx] = (mask <= 0.5f) ? 1.0f : 0.0f;
}

// ---------------------------------------------------------------------------
extern "C" void kernel_launch(void* const* d_in, const int* in_sizes, int n_in,
                              void* d_out, int out_size, void* d_ws, size_t ws_size,
                              hipStream_t stream) {
    const float* x1_0 = (const float*)d_in[0];
    const float* x1_1 = (const float*)d_in[2];
    const float* x1_2 = (const float*)d_in[4];
    const float* m1t  = (const float*)d_in[6];
    const float* m2t  = (const float*)d_in[7];
    const float* F12  = (const float*)d_in[8];
    const float* F21  = (const float*)d_in[9];

    const int N = 4;
    const int H0 = 256, W0 = 448;
    const int H1 = 128, W1 = 224;
    const int H2 = 64,  W2 = 112;
    const int HW0 = H0 * W0, HW1 = H1 * W1, HW2 = H2 * W2;
    const int NHW0 = N * HW0, NHW1 = N * HW1, NHW2 = N * HW2;

    // d_out layout (floats), reference return order
    const size_t o0 = 0;
    const size_t o1 = o0 + (size_t)N * 32 * HW0;
    const size_t o2 = o1 + (size_t)N * 64 * HW1;
    const size_t o3 = o2 + (size_t)N * 96 * HW2;
    const size_t o4 = o3 + (size_t)NHW0;
    const size_t o5 = o4 + (size_t)NHW1;
    const size_t o6 = o5 + (size_t)NHW2;
    float* out = (float*)d_out;

    const int B = 256;

    // padded channel strides
    const int CS0 = 34, CS1 = 66, CS2 = 98, CSF = 4;

    // fast-path ws layout (floats): nums first (single memset), then featT, then small
    size_t num0_sz = (size_t)NHW0 * CS0;
    size_t num1_sz = (size_t)NHW1 * CS1;
    size_t num2_sz = (size_t)NHW2 * CS2;
    size_t numF_sz = (size_t)NHW0 * CSF;
    size_t featT_sz = num0_sz + num1_sz + num2_sz;
    size_t small_sz = (size_t)NHW1 + NHW2 + 2 * NHW1 + 2 * NHW2;
    size_t need = (num0_sz + num1_sz + num2_sz + numF_sz) + featT_sz + small_sz;

    if (ws_size >= need * sizeof(float)) {
        float* ws_f    = (float*)d_ws;
        float* num0    = ws_f;
        float* num1    = num0 + num0_sz;
        float* num2    = num1 + num1_sz;
        float* numF    = num2 + num2_sz;
        float* featT0  = numF + numF_sz;
        float* featT1  = featT0 + num0_sz;
        float* featT2  = featT1 + num1_sz;
        float* metric1 = featT2 + num2_sz;
        float* metric2 = metric1 + NHW1;
        float* flow1   = metric2 + NHW2;
        float* flow2   = flow1 + 2 * NHW1;

        // zero the atomic accumulators
        hipMemsetAsync(ws_f, 0, (num0_sz + num1_sz + num2_sz + numF_sz) * sizeof(float), stream);

        // pyramid resizes (flow scale folded: F1t=0.5*F12)
        downsample2_kernel<<<cdiv_i(N * 1 * HW1, B), B, 0, stream>>>(m1t, metric1, N, H0, W0, 1.0f);
        downsample2_kernel<<<cdiv_i(N * 2 * HW1, B), B, 0, stream>>>(F12, flow1, N * 2, H0, W0, 0.25f);
        downsample2_kernel<<<cdiv_i(N * 1 * HW2, B), B, 0, stream>>>(metric1, metric2, N, H1, W1, 1.0f);
        downsample2_kernel<<<cdiv_i(N * 2 * HW2, B), B, 0, stream>>>(flow1, flow2, N * 2, H1, W1, 0.5f);

        // feature transposes NCHW -> NHWC(CS)
        t_nchw2nhwc<32, 34, 35><<<NHW0 / 64, 256, 0, stream>>>(x1_0, featT0, HW0);
        t_nchw2nhwc<64, 66, 67><<<NHW1 / 64, 256, 0, stream>>>(x1_1, featT1, HW1);
        t_nchw2nhwc<96, 98, 99><<<NHW2 / 64, 256, 0, stream>>>(x1_2, featT2, HW2);

        // coalesced splats
        splat_nhwc<32, 34, 32, true,  false><<<NHW0 / 8,  256, 0, stream>>>(
            featT0, 1.0f, F12, 0.5f, m1t, num0, N, H0, W0);
        splat_nhwc<64, 66, 64, true,  false><<<NHW1 / 4,  256, 0, stream>>>(
            featT1, 1.0f, flow1, 1.0f, metric1, num1, N, H1, W1);
        splat_nhwc<96, 98, 64, true,  false><<<NHW2 / 4,  256, 0, stream>>>(
            featT2, 1.0f, flow2, 1.0f, metric2, num2, N, H2, W2);
        splat_nhwc<2,  4,  4,  false, true ><<<NHW0 / 64, 256, 0, stream>>>(
            nullptr, 1.0f, F21, 0.5f, m2t, numF, N, H0, W0);

        // normalize + transpose back + hole masks
        norm_nhwc2nchw<32, 34, 35, true ><<<NHW0 / 64, 256, 0, stream>>>(num0, out + o0, out + o3, HW0,  1.0f);
        norm_nhwc2nchw<64, 66, 67, true ><<<NHW1 / 64, 256, 0, stream>>>(num1, out + o1, out + o4, HW1,  1.0f);
        norm_nhwc2nchw<96, 98, 99, true ><<<NHW2 / 64, 256, 0, stream>>>(num2, out + o2, out + o5, HW2,  1.0f);
        norm_nhwc2nchw<2,  4,  5,  false><<<NHW0 / 64, 256, 0, stream>>>(numF, out + o6, nullptr,  HW0, -1.0f);
    } else {
        // -------- fallback: round-1 path --------
        float* ws_f     = (float*)d_ws;
        float* denom0   = ws_f;
        float* denom1   = denom0 + NHW0;
        float* denom2   = denom1 + NHW1;
        float* denomF   = denom2 + NHW2;
        float* metric1  = denomF + NHW0;
        float* metric2  = metric1 + NHW1;
        float* flow1    = metric2 + NHW2;
        float* flow2    = flow1 + 2 * NHW1;
        const size_t zeroN = (size_t)NHW0 + NHW1 + NHW2 + NHW0;

        hipMemsetAsync(d_out, 0, (size_t)out_size * sizeof(float), stream);
        hipMemsetAsync(ws_f, 0, zeroN * sizeof(float), stream);

        downsample2_kernel<<<cdiv_i(N * 1 * HW1, B), B, 0, stream>>>(m1t, metric1, N, H0, W0, 1.0f);
        downsample2_kernel<<<cdiv_i(N * 2 * HW1, B), B, 0, stream>>>(F12, flow1, N * 2, H0, W0, 0.25f);
        downsample2_kernel<<<cdiv_i(N * 1 * HW2, B), B, 0, stream>>>(metric1, metric2, N, H1, W1, 1.0f);
        downsample2_kernel<<<cdiv_i(N * 2 * HW2, B), B, 0, stream>>>(flow1, flow2, N * 2, H1, W1, 0.5f);

        splat_kernel<32, true><<<cdiv_i(NHW0, B), B, 0, stream>>>(
            x1_0, 1.0f, F12, 0.5f, m1t, out + o0, denom0, out + o3, N, H0, W0);
        splat_kernel<64, true><<<cdiv_i(NHW1, B), B, 0, stream>>>(
            x1_1, 1.0f, flow1, 1.0f, metric1, out + o1, denom1, out + o4, N, H1, W1);
        splat_kernel<96, true><<<cdiv_i(NHW2, B), B, 0, stream>>>(
            x1_2, 1.0f, flow2, 1.0f, metric2, out + o2, denom2, out + o5, N, H2, W2);
        splat_kernel<2, false><<<cdiv_i(NHW0, B), B, 0, stream>>>(
            F21, 0.5f, F21, 0.5f, m2t, out + o6, denomF, nullptr, N, H0, W0);

        normalize_kernel<<<cdiv_i(N * 32 * HW0, B), B, 0, stream>>>(out + o0, denom0, 32, HW0, N * 32 * HW0, 1.0f);
        normalize_kernel<<<cdiv_i(N * 64 * HW1, B), B, 0, stream>>>(out + o1, denom1, 64, HW1, N * 64 * HW1, 1.0f);
        normalize_kernel<<<cdiv_i(N * 96 * HW2, B), B, 0, stream>>>(out + o2, denom2, 96, HW2, N * 96 * HW2, 1.0f);
        normalize_kernel<<<cdiv_i(N * 2 * HW0, B), B, 0, stream>>>(out + o6, denomF, 2, HW0, N * 2 * HW0, -1.0f);

        hole_kernel<<<cdiv_i(NHW0, B), B, 0, stream>>>(out + o3, NHW0);
        hole_kernel<<<cdiv_i(NHW1, B), B, 0, stream>>>(out + o4, NHW1);
        hole_kernel<<<cdiv_i(NHW2, B), B, 0, stream>>>(out + o5, NHW2);
    }
}

// Round 3
// 822.184 us; speedup vs baseline: 4.0430x; 1.1531x over previous
//
#include <hip/hip_runtime.h>

#define EPS 1e-7f

static inline int cdiv_i(int a, int b) { return (a + b - 1) / b; }

__device__ __forceinline__ float eweight(float m) {
    return expf(fminf(fmaxf(-m, -20.0f), 20.0f));
}

// ---------------------------------------------------------------------------
// Exact factor-2 bilinear+antialias downsample (jax.image.resize semantics)
// ---------------------------------------------------------------------------
__global__ void downsample2_kernel(const float* __restrict__ in, float* __restrict__ out,
                                   int NC, int Hin, int Win, float scale) {
    const int Hout = Hin >> 1, Wout = Win >> 1;
    const int HWo = Hout * Wout;
    int idx = blockIdx.x * blockDim.x + threadIdx.x;
    if (idx >= NC * HWo) return;
    int nc = idx / HWo;
    int p = idx - nc * HWo;
    int i = p / Wout;
    int j = p - i * Wout;

    const float kk[4] = { 0.25f, 0.75f, 0.75f, 0.25f };
    float wy[4], wx[4], sy = 0.0f, sx = 0.0f;
    int r0 = 2 * i - 1, c0 = 2 * j - 1;
#pragma unroll
    for (int a = 0; a < 4; ++a) {
        int ra = r0 + a;
        wy[a] = (ra >= 0 && ra < Hin) ? kk[a] : 0.0f;
        sy += wy[a];
        int cb = c0 + a;
        wx[a] = (cb >= 0 && cb < Win) ? kk[a] : 0.0f;
        sx += wx[a];
    }
#pragma unroll
    for (int a = 0; a < 4; ++a) { wy[a] /= sy; wx[a] /= sx; }

    const float* base = in + (size_t)nc * Hin * Win;
    float acc = 0.0f;
#pragma unroll
    for (int a = 0; a < 4; ++a) {
        int ra = r0 + a;
        if (ra < 0 || ra >= Hin) continue;
        const float* row = base + (size_t)ra * Win;
        float racc = 0.0f;
#pragma unroll
        for (int b = 0; b < 4; ++b) {
            int cb = c0 + b;
            if (cb < 0 || cb >= Win) continue;
            racc += wx[b] * row[cb];
        }
        acc += wy[a] * racc;
    }
    out[(size_t)nc * HWo + p] = acc * scale;
}

// ---------------------------------------------------------------------------
// NCHW -> NHWC (stride C, tight) feature transpose with e = exp(clip(-m))
// folded in. 64 px per block, 256 threads.
// ---------------------------------------------------------------------------
template <int C>
__global__ __launch_bounds__(256) void t_feat(const float* __restrict__ in,
                                              const float* __restrict__ metric,
                                              float* __restrict__ out, int HW) {
    __shared__ float lds[64 * (C + 1)];
    __shared__ float ldse[64];
    int q0 = blockIdx.x * 64;
    int n = q0 / HW;
    int p0 = q0 - n * HW;
    int l = threadIdx.x & 63;
    int cg = threadIdx.x >> 6;
    for (int c = cg; c < C; c += 4) {
        lds[l * (C + 1) + c] = in[((size_t)n * C + c) * HW + p0 + l];
    }
    if (threadIdx.x < 64) {
        float m = metric[(size_t)n * HW + p0 + threadIdx.x];
        ldse[threadIdx.x] = eweight(m);
    }
    __syncthreads();
    const int TOT = 64 * C;
    for (int idx = threadIdx.x; idx < TOT; idx += 256) {
        int px = idx / C;
        int c = idx - px * C;
        out[(size_t)q0 * C + idx] = lds[px * (C + 1) + c] * ldse[px];
    }
}

// ---------------------------------------------------------------------------
// Wave-centric pair-merged soft-splat.
// featT [N*HW, C] already multiplied by e. num [targets, C] (C line-aligned),
// dh [targets, 2] = (sum e*w, sum w).
// Each wave handles 64 consecutive source pixels: per-lane math, then a
// broadcast loop issuing contiguous pair-merged atomic segments.
// ---------------------------------------------------------------------------
template <int C, int H, int W>
__global__ __launch_bounds__(256) void splat_wave(const float* __restrict__ featT,
                                                  const float* __restrict__ flow, float flow_scale,
                                                  const float* __restrict__ metric,
                                                  float* __restrict__ num,
                                                  float* __restrict__ dh) {
    constexpr int HW = H * W;
    const int lane = threadIdx.x & 63;
    const int wid = blockIdx.x * 4 + (threadIdx.x >> 6);
    const int q0 = wid * 64;
    const int n = q0 / HW;
    const int p0 = q0 - n * HW;

    // phase A: per-lane source-pixel math (coalesced loads)
    const int p = p0 + lane;
    int y = p / W;
    int x = p - y * W;
    float dx = flow[(size_t)(n * 2 + 0) * HW + p] * flow_scale;
    float dy = flow[(size_t)(n * 2 + 1) * HW + p] * flow_scale;
    float m = metric[(size_t)n * HW + p];
    float e = eweight(m);
    float gx = (float)x + dx;
    float gy = (float)y + dy;
    float x0f = floorf(gx), y0f = floorf(gy);
    float fx = gx - x0f, fy = gy - y0f;
    int x0 = (int)x0f, y0 = (int)y0f;

    const float* fT = featT + (size_t)q0 * C;

#pragma unroll 4
    for (int i = 0; i < 64; ++i) {
        float fxi = __shfl(fx, i);
        float fyi = __shfl(fy, i);
        float ei = __shfl(e, i);
        int x0b = __shfl(x0, i);
        int y0b = __shfl(y0, i);

        float wx0 = 1.0f - fxi, wx1 = fxi;
        float wy0 = 1.0f - fyi, wy1 = fyi;
        bool yv0 = (unsigned)y0b < (unsigned)H;
        bool yv1 = (unsigned)(y0b + 1) < (unsigned)H;
        long long tbase = ((long long)n * H + y0b) * (long long)W + x0b;

        if constexpr (C == 32) {
            int crn = lane >> 5;
            int cc = lane & 31;
            float f = fT[i * 32 + cc];
            bool xv = (unsigned)(x0b + crn) < (unsigned)W;
            float wxc = crn ? wx1 : wx0;
            long long t = tbase + crn;
            if (xv && yv0) atomicAdd(&num[t * 32 + cc], f * wxc * wy0);
            if (xv && yv1) atomicAdd(&num[(t + W) * 32 + cc], f * wxc * wy1);
        } else if constexpr (C == 64) {
            float f = fT[i * 64 + lane];
#pragma unroll
            for (int crn = 0; crn < 2; ++crn) {
                bool xv = (unsigned)(x0b + crn) < (unsigned)W;
                float wxc = crn ? wx1 : wx0;
                long long t = tbase + crn;
                if (xv && yv0) atomicAdd(&num[t * 64 + lane], f * wxc * wy0);
                if (xv && yv1) atomicAdd(&num[(t + W) * 64 + lane], f * wxc * wy1);
            }
        } else {  // C == 96
            float fa = fT[i * 96 + lane];
            float fb = fT[i * 96 + 64 + (lane & 31)];
#pragma unroll
            for (int crn = 0; crn < 2; ++crn) {
                bool xv = (unsigned)(x0b + crn) < (unsigned)W;
                float wxc = crn ? wx1 : wx0;
                long long t = tbase + crn;
                if (xv && yv0) {
                    atomicAdd(&num[t * 96 + lane], fa * wxc * wy0);
                    if (lane < 32) atomicAdd(&num[t * 96 + 64 + lane], fb * wxc * wy0);
                }
                if (xv && yv1) {
                    atomicAdd(&num[(t + W) * 96 + lane], fa * wxc * wy1);
                    if (lane < 32) atomicAdd(&num[(t + W) * 96 + 64 + lane], fb * wxc * wy1);
                }
            }
        }

        // denom + hole: one instr, lanes 0..7 cover 2 rows x (2 corners x 2 ch)
        if (lane < 8) {
            int row = lane >> 2, slot = lane & 3, crn2 = slot >> 1, ch = slot & 1;
            int yt = y0b + row;
            int xt = x0b + crn2;
            if ((unsigned)xt < (unsigned)W && (unsigned)yt < (unsigned)H) {
                float wr = (crn2 ? wx1 : wx0) * (row ? wy1 : wy0);
                atomicAdd(&dh[(((long long)n * H + yt) * (long long)W + x0b) * 2 + slot],
                          ch ? wr : wr * ei);
            }
        }
    }
}

// ---------------------------------------------------------------------------
// Ft2 splat: channels {dx*e, dy*e, e, pad} packed CS=4, pair-merged.
// ---------------------------------------------------------------------------
template <int H, int W>
__global__ __launch_bounds__(256) void splat_flow(const float* __restrict__ flow, float flow_scale,
                                                  const float* __restrict__ metric,
                                                  float* __restrict__ num) {
    constexpr int HW = H * W;
    const int lane = threadIdx.x & 63;
    const int wid = blockIdx.x * 4 + (threadIdx.x >> 6);
    const int q0 = wid * 64;
    const int n = q0 / HW;
    const int p0 = q0 - n * HW;

    const int p = p0 + lane;
    int y = p / W;
    int x = p - y * W;
    float dx = flow[(size_t)(n * 2 + 0) * HW + p] * flow_scale;
    float dy = flow[(size_t)(n * 2 + 1) * HW + p] * flow_scale;
    float m = metric[(size_t)n * HW + p];
    float e = eweight(m);
    float dxe = dx * e, dye = dy * e;
    float gx = (float)x + dx;
    float gy = (float)y + dy;
    float x0f = floorf(gx), y0f = floorf(gy);
    float fx = gx - x0f, fy = gy - y0f;
    int x0 = (int)x0f, y0 = (int)y0f;

#pragma unroll 4
    for (int i = 0; i < 64; ++i) {
        float fxi = __shfl(fx, i);
        float fyi = __shfl(fy, i);
        float ei = __shfl(e, i);
        float dxei = __shfl(dxe, i);
        float dyei = __shfl(dye, i);
        int x0b = __shfl(x0, i);
        int y0b = __shfl(y0, i);

        if (lane < 16) {
            int row = lane >> 3, slot = lane & 7, crn = slot >> 2, ch = slot & 3;
            int yt = y0b + row;
            int xt = x0b + crn;
            if ((unsigned)xt < (unsigned)W && (unsigned)yt < (unsigned)H) {
                float wr = (crn ? fxi : 1.0f - fxi) * (row ? fyi : 1.0f - fyi);
                float v = (ch == 0) ? dxei : (ch == 1) ? dyei : (ch == 2) ? ei : 0.0f;
                atomicAdd(&num[(((long long)n * H + yt) * (long long)W + x0b) * 4 + slot], wr * v);
            }
        }
    }
}

// ---------------------------------------------------------------------------
// NHWC accum -> NCHW normalized output + hole mask. 64 px / block.
// ---------------------------------------------------------------------------
template <int C>
__global__ __launch_bounds__(256) void norm_feat(const float* __restrict__ num,
                                                 const float* __restrict__ dh,
                                                 float* __restrict__ out,
                                                 float* __restrict__ hole, int HW) {
    __shared__ float ldsn[64 * (C + 1)];
    __shared__ float ldsd[128];
    int q0 = blockIdx.x * 64;
    int n = q0 / HW;
    int p0 = q0 - n * HW;
    const int TOT = 64 * C;
    for (int idx = threadIdx.x; idx < TOT; idx += 256) {
        int px = idx / C;
        int c = idx - px * C;
        ldsn[px * (C + 1) + c] = num[(size_t)q0 * C + idx];
    }
    if (threadIdx.x < 128) ldsd[threadIdx.x] = dh[(size_t)q0 * 2 + threadIdx.x];
    __syncthreads();
    int l = threadIdx.x & 63;
    int cg = threadIdx.x >> 6;
    float inv = 1.0f / (ldsd[l * 2] + EPS);
    for (int c = cg; c < C; c += 4) {
        out[((size_t)n * C + c) * HW + p0 + l] = ldsn[l * (C + 1) + c] * inv;
    }
    if (threadIdx.x < 64) {
        float s = ldsd[threadIdx.x * 2 + 1];
        float mask = s / (s + EPS);
        hole[q0 + threadIdx.x] = (mask <= 0.5f) ? 1.0f : 0.0f;
    }
}

__global__ __launch_bounds__(256) void norm_flow(const float* __restrict__ num,
                                                 float* __restrict__ out, int HW, int total) {
    int q = blockIdx.x * blockDim.x + threadIdx.x;
    if (q >= total) return;
    float4 v = ((const float4*)num)[q];
    int n = q / HW;
    int p = q - n * HW;
    float inv = -1.0f / (v.z + EPS);
    out[((size_t)n * 2 + 0) * HW + p] = v.x * inv;
    out[((size_t)n * 2 + 1) * HW + p] = v.y * inv;
}

// ---------------------------------------------------------------------------
extern "C" void kernel_launch(void* const* d_in, const int* in_sizes, int n_in,
                              void* d_out, int out_size, void* d_ws, size_t ws_size,
                              hipStream_t stream) {
    const float* x1_0 = (const float*)d_in[0];
    const float* x1_1 = (const float*)d_in[2];
    const float* x1_2 = (const float*)d_in[4];
    const float* m1t  = (const float*)d_in[6];
    const float* m2t  = (const float*)d_in[7];
    const float* F12  = (const float*)d_in[8];
    const float* F21  = (const float*)d_in[9];

    const int N = 4;
    const int H0 = 256, W0 = 448;
    const int H1 = 128, W1 = 224;
    const int H2 = 64,  W2 = 112;
    const int HW0 = H0 * W0, HW1 = H1 * W1, HW2 = H2 * W2;
    const int NHW0 = N * HW0, NHW1 = N * HW1, NHW2 = N * HW2;

    // d_out layout (floats), reference return order
    const size_t o0 = 0;
    const size_t o1 = o0 + (size_t)N * 32 * HW0;
    const size_t o2 = o1 + (size_t)N * 64 * HW1;
    const size_t o3 = o2 + (size_t)N * 96 * HW2;
    const size_t o4 = o3 + (size_t)NHW0;
    const size_t o5 = o4 + (size_t)NHW1;
    const size_t o6 = o5 + (size_t)NHW2;
    float* out = (float*)d_out;

    // ws layout (floats): zero-region first (one memset), then featT, then small
    float* ws_f   = (float*)d_ws;
    float* num0   = ws_f;                       // NHW0*32
    float* dh0    = num0 + (size_t)NHW0 * 32;   // NHW0*2
    float* num1   = dh0 + (size_t)NHW0 * 2;     // NHW1*64
    float* dh1    = num1 + (size_t)NHW1 * 64;   // NHW1*2
    float* num2   = dh1 + (size_t)NHW1 * 2;     // NHW2*96
    float* dh2    = num2 + (size_t)NHW2 * 96;   // NHW2*2
    float* numF   = dh2 + (size_t)NHW2 * 2;     // NHW0*4
    float* featT0 = numF + (size_t)NHW0 * 4;    // NHW0*32
    float* featT1 = featT0 + (size_t)NHW0 * 32; // NHW1*64
    float* featT2 = featT1 + (size_t)NHW1 * 64; // NHW2*96
    float* metric1 = featT2 + (size_t)NHW2 * 96;
    float* metric2 = metric1 + NHW1;
    float* flow1   = metric2 + NHW2;
    float* flow2   = flow1 + 2 * NHW1;

    const size_t zeroN = (size_t)NHW0 * 32 + (size_t)NHW0 * 2 + (size_t)NHW1 * 64 +
                         (size_t)NHW1 * 2 + (size_t)NHW2 * 96 + (size_t)NHW2 * 2 +
                         (size_t)NHW0 * 4;
    hipMemsetAsync(ws_f, 0, zeroN * sizeof(float), stream);

    const int B = 256;

    // pyramid resizes (flow scale folded: F1t = 0.5*F12)
    downsample2_kernel<<<cdiv_i(N * 1 * HW1, B), B, 0, stream>>>(m1t, metric1, N, H0, W0, 1.0f);
    downsample2_kernel<<<cdiv_i(N * 2 * HW1, B), B, 0, stream>>>(F12, flow1, N * 2, H0, W0, 0.25f);
    downsample2_kernel<<<cdiv_i(N * 1 * HW2, B), B, 0, stream>>>(metric1, metric2, N, H1, W1, 1.0f);
    downsample2_kernel<<<cdiv_i(N * 2 * HW2, B), B, 0, stream>>>(flow1, flow2, N * 2, H1, W1, 0.5f);

    // transposes with e folded in
    t_feat<32><<<NHW0 / 64, 256, 0, stream>>>(x1_0, m1t, featT0, HW0);
    t_feat<64><<<NHW1 / 64, 256, 0, stream>>>(x1_1, metric1, featT1, HW1);
    t_feat<96><<<NHW2 / 64, 256, 0, stream>>>(x1_2, metric2, featT2, HW2);

    // splats
    splat_wave<32, 256, 448><<<NHW0 / 256, 256, 0, stream>>>(featT0, F12, 0.5f, m1t, num0, dh0);
    splat_wave<64, 128, 224><<<NHW1 / 256, 256, 0, stream>>>(featT1, flow1, 1.0f, metric1, num1, dh1);
    splat_wave<96, 64, 112><<<NHW2 / 256, 256, 0, stream>>>(featT2, flow2, 1.0f, metric2, num2, dh2);
    splat_flow<256, 448><<<NHW0 / 256, 256, 0, stream>>>(F21, 0.5f, m2t, numF);

    // normalize + transpose back + hole masks
    norm_feat<32><<<NHW0 / 64, 256, 0, stream>>>(num0, dh0, out + o0, out + o3, HW0);
    norm_feat<64><<<NHW1 / 64, 256, 0, stream>>>(num1, dh1, out + o1, out + o4, HW1);
    norm_feat<96><<<NHW2 / 64, 256, 0, stream>>>(num2, dh2, out + o2, out + o5, HW2);
    norm_flow<<<cdiv_i(NHW0, B), B, 0, stream>>>(numF, out + o6, HW0, NHW0);
}